// Round 4
// baseline (20042.406 us; speedup 1.0000x reference)
//
#include <hip/hip_runtime.h>
#include <math.h>

#define Bb 128
#define Nn 100
#define Ee 512
#define Hh 8
#define DHd 64
#define FFf 2048
#define Ll 6
#define STEPS 150

typedef _Float16 h8 __attribute__((ext_vector_type(8)));
typedef _Float16 h4 __attribute__((ext_vector_type(4)));
typedef float f4 __attribute__((ext_vector_type(4)));

// ---------------------------------------------------------------------------
// Split-f16 MFMA GEMM.  C[M,N] = A[M,K] @ B[K,N] computed as
// Ah*Bh + Ah*Bl + Al*Bh with f16 hi/lo planes (pre-split inputs).
// ---------------------------------------------------------------------------
template<bool RELU, bool BIAS, bool OUTF32, bool SPLITK>
__global__ __launch_bounds__(256) void mgemm_k(
    const _Float16* __restrict__ Ah, const _Float16* __restrict__ Al, int lda,
    const _Float16* __restrict__ Bh, const _Float16* __restrict__ Bl, int ldb,
    float* __restrict__ C, _Float16* __restrict__ Ch, _Float16* __restrict__ Cl,
    int ldc, const float* __restrict__ bias, int K, int kc, int Mtot)
{
  __shared__ _Float16 sm[4 * 5120];            // 4 planes of 128 x (32+8pad)
  _Float16* sAh = sm;
  _Float16* sAl = sm + 5120;
  _Float16* sBh = sm + 10240;
  _Float16* sBl = sm + 15360;
  const int tid = threadIdx.x;
  const int m0 = blockIdx.y * 128, n0 = blockIdx.x * 128;
  const int k0 = SPLITK ? blockIdx.z * kc : 0;
  const int kEnd = SPLITK ? k0 + kc : K;
  const int lane = tid & 63, wave = tid >> 6;
  const int wm = wave >> 1, wn = wave & 1;
  const int m16 = lane & 15, kg = lane >> 4;
  f4 acc[4][4];
#pragma unroll
  for (int i = 0; i < 4; ++i)
#pragma unroll
    for (int j = 0; j < 4; ++j) acc[i][j] = (f4)0.f;

  for (int kt = k0; kt < kEnd; kt += 32) {
#pragma unroll
    for (int it = 0; it < 2; ++it) {
      int idx = tid + it * 256;                // 512 (row,g) slots
      int row = idx >> 2, g = idx & 3;
      int lo_ = row * 40 + g * 8;
      size_t ga = (size_t)(m0 + row) * lda + kt + g * 8;
      size_t gb = (size_t)(n0 + row) * ldb + kt + g * 8;
      *(h8*)(sAh + lo_) = *(const h8*)(Ah + ga);
      *(h8*)(sAl + lo_) = *(const h8*)(Al + ga);
      *(h8*)(sBh + lo_) = *(const h8*)(Bh + gb);
      *(h8*)(sBl + lo_) = *(const h8*)(Bl + gb);
    }
    __syncthreads();
    h8 a_h[4], a_l[4], b_h[4], b_l[4];
#pragma unroll
    for (int i = 0; i < 4; ++i) {
      int ro = (wm * 64 + i * 16 + m16) * 40 + kg * 8;
      int co = (wn * 64 + i * 16 + m16) * 40 + kg * 8;
      a_h[i] = *(const h8*)(sAh + ro);
      a_l[i] = *(const h8*)(sAl + ro);
      b_h[i] = *(const h8*)(sBh + co);
      b_l[i] = *(const h8*)(sBl + co);
    }
#pragma unroll
    for (int i = 0; i < 4; ++i)
#pragma unroll
      for (int j = 0; j < 4; ++j) {
        acc[i][j] = __builtin_amdgcn_mfma_f32_16x16x32_f16(a_h[i], b_h[j], acc[i][j], 0, 0, 0);
        acc[i][j] = __builtin_amdgcn_mfma_f32_16x16x32_f16(a_h[i], b_l[j], acc[i][j], 0, 0, 0);
        acc[i][j] = __builtin_amdgcn_mfma_f32_16x16x32_f16(a_l[i], b_h[j], acc[i][j], 0, 0, 0);
      }
    __syncthreads();
  }

  float* Cz = OUTF32 ? (C + (SPLITK ? (size_t)blockIdx.z * (size_t)Mtot * ldc : (size_t)0)) : C;
  int rb = m0 + wm * 64 + kg * 4;              // C/D: row=(lane>>4)*4+reg
  int cb = n0 + wn * 64 + m16;                 //      col=lane&15
#pragma unroll
  for (int j = 0; j < 4; ++j) {
    int col = cb + j * 16;
    float bv = BIAS ? bias[col] : 0.f;
#pragma unroll
    for (int i = 0; i < 4; ++i) {
#pragma unroll
      for (int r = 0; r < 4; ++r) {
        float v = acc[i][j][r] + bv;
        if (RELU) v = fmaxf(v, 0.f);
        int row = rb + i * 16 + r;
        if (OUTF32) {
          Cz[(size_t)row * ldc + col] = v;
        } else {
          _Float16 hh = (_Float16)v;
          Ch[(size_t)row * ldc + col] = hh;
          Cl[(size_t)row * ldc + col] = (_Float16)(v - (float)hh);
        }
      }
    }
  }
}

// ---------------------------------------------------------------------------
// Weight transpose + split:  W [K][N] fp32  ->  Th/Tl [N][K] f16
// ---------------------------------------------------------------------------
__global__ __launch_bounds__(256) void wconv_k(
    const float* __restrict__ W, int K, int N,
    _Float16* __restrict__ Th, _Float16* __restrict__ Tl)
{
  __shared__ float t[32][33];
  int n0 = blockIdx.x * 32, k0 = blockIdx.y * 32;
  int tid = threadIdx.x;
  int r = tid >> 3, c4 = (tid & 7) * 4;
  float4 v = *(const float4*)(W + (size_t)(k0 + r) * N + n0 + c4);
  t[r][c4 + 0] = v.x; t[r][c4 + 1] = v.y; t[r][c4 + 2] = v.z; t[r][c4 + 3] = v.w;
  __syncthreads();
  h4 hi, lo;
#pragma unroll
  for (int i = 0; i < 4; ++i) {
    float x = t[c4 + i][r];
    _Float16 hh = (_Float16)x;
    hi[i] = hh;
    lo[i] = (_Float16)(x - (float)hh);
  }
  *(h4*)(Th + (size_t)(n0 + r) * K + k0 + c4) = hi;
  *(h4*)(Tl + (size_t)(n0 + r) * K + k0 + c4) = lo;
}

// FF2 split-K(4) partial reduce + bias, chunk of 3200x512
__global__ __launch_bounds__(256) void reduce4_k(
    const float* __restrict__ P, const float* __restrict__ bias, float* __restrict__ out)
{
  int idx = blockIdx.x * 256 + threadIdx.x;   // < 3200*512
  const size_t S = 3200ull * 512;
  float v = P[idx] + P[idx + S] + P[idx + 2 * S] + P[idx + 3 * S] + bias[idx & 511];
  out[idx] = v;
}

// ---------------------------------------------------------------------------
// x = node_features @ in_w + in_b + pe   (+ f16 hi/lo planes)
// ---------------------------------------------------------------------------
__global__ __launch_bounds__(256) void input_proj_k(
    const float* __restrict__ nf, const float* __restrict__ inw,
    const float* __restrict__ inb, const float* __restrict__ pe,
    float* __restrict__ x, _Float16* __restrict__ xh, _Float16* __restrict__ xl)
{
  int idx = blockIdx.x * 256 + threadIdx.x;   // < 12800*512
  int bn = idx >> 9, e = idx & 511;
  int n = bn - (bn / Nn) * Nn;
  const float* fr = nf + (size_t)bn * 8;
  float s = inb[e] + pe[(size_t)n * 512 + e];
#pragma unroll
  for (int i = 0; i < 8; ++i) s += fr[i] * inw[(size_t)i * 512 + e];
  x[idx] = s;
  _Float16 hh = (_Float16)s;
  xh[idx] = hh;
  xl[idx] = (_Float16)(s - (float)hh);
}

// ---------------------------------------------------------------------------
// Residual + LayerNorm (rows of 512) + f16 hi/lo planes
// ---------------------------------------------------------------------------
__global__ __launch_bounds__(256) void ln_k(
    const float* __restrict__ xin, const float* __restrict__ yin,
    const float* __restrict__ g, const float* __restrict__ bb,
    float* __restrict__ out, _Float16* __restrict__ oh, _Float16* __restrict__ ol)
{
  int row = blockIdx.x, t = threadIdx.x;
  __shared__ float red[256];
  size_t base = (size_t)row * 512;
  float v0 = xin[base + t] + yin[base + t];
  float v1 = xin[base + 256 + t] + yin[base + 256 + t];
  red[t] = v0 + v1;
  __syncthreads();
  for (int o = 128; o > 0; o >>= 1) { if (t < o) red[t] += red[t + o]; __syncthreads(); }
  float mu = red[0] * (1.f / 512.f);
  __syncthreads();
  float d0 = v0 - mu, d1 = v1 - mu;
  red[t] = d0 * d0 + d1 * d1;
  __syncthreads();
  for (int o = 128; o > 0; o >>= 1) { if (t < o) red[t] += red[t + o]; __syncthreads(); }
  float inv = 1.f / sqrtf(red[0] * (1.f / 512.f) + 1e-5f);
  float y0 = d0 * inv * g[t] + bb[t];
  float y1 = d1 * inv * g[t + 256] + bb[t + 256];
  out[base + t] = y0;
  out[base + 256 + t] = y1;
  _Float16 h0 = (_Float16)y0, h1 = (_Float16)y1;
  oh[base + t] = h0;           ol[base + t] = (_Float16)(y0 - (float)h0);
  oh[base + 256 + t] = h1;     ol[base + 256 + t] = (_Float16)(y1 - (float)h1);
}

// ---------------------------------------------------------------------------
// Fused encoder attention per (b,h); output written as f16 hi/lo planes.
// ---------------------------------------------------------------------------
__global__ __launch_bounds__(256) void enc_attn_k(
    const float* __restrict__ q, const float* __restrict__ k,
    const float* __restrict__ v, _Float16* __restrict__ oh, _Float16* __restrict__ ol)
{
  __shared__ __align__(16) float smem[14848];
  int bh = blockIdx.x; int b = bh >> 3, h = bh & 7;
  int t = threadIdx.x;
  float* qs = smem;           // stride 68
  float* kT = smem + 7616;    // stride 113
  float* p  = smem;           // stride 104 (overlay after phase 1)
  const float* qg = q + ((size_t)b * Nn) * 512 + h * 64;
  const float* kg = k + ((size_t)b * Nn) * 512 + h * 64;
  const float* vg = v + ((size_t)b * Nn) * 512 + h * 64;
  for (int idx = t; idx < 6400; idx += 256) {
    int i = idx >> 6, d = idx & 63;
    qs[i * 68 + d]  = qg[(size_t)i * 512 + d];
    kT[d * 113 + i] = kg[(size_t)i * 512 + d];
  }
  __syncthreads();
  int ti = t >> 4, tj = t & 15;
  int i0 = ti * 7, j0 = tj * 7;
  float s[7][7];
#pragma unroll
  for (int r = 0; r < 7; ++r)
#pragma unroll
    for (int c = 0; c < 7; ++c) s[r][c] = 0.f;
  for (int kk = 0; kk < 64; ++kk) {
    float a[7], bb[7];
#pragma unroll
    for (int r = 0; r < 7; ++r) a[r] = qs[(i0 + r) * 68 + kk];
#pragma unroll
    for (int c = 0; c < 7; ++c) bb[c] = kT[kk * 113 + j0 + c];
#pragma unroll
    for (int r = 0; r < 7; ++r)
#pragma unroll
      for (int c = 0; c < 7; ++c) s[r][c] += a[r] * bb[c];
  }
  __syncthreads();
#pragma unroll
  for (int r = 0; r < 7; ++r)
#pragma unroll
    for (int c = 0; c < 7; ++c) {
      int i = i0 + r, j = j0 + c;
      if (i < Nn && j < Nn) p[i * 104 + j] = s[r][c] * 0.125f;
    }
  __syncthreads();
  int w = t >> 6, lane = t & 63;
  for (int i = w; i < Nn; i += 4) {
    float x0 = p[i * 104 + lane];
    float x1 = (lane < 36) ? p[i * 104 + 64 + lane] : -3.4e38f;
    float mx = fmaxf(x0, x1);
    for (int msk = 32; msk; msk >>= 1) mx = fmaxf(mx, __shfl_xor(mx, msk));
    float e0 = expf(x0 - mx);
    float e1 = (lane < 36) ? expf(x1 - mx) : 0.f;
    float ss = e0 + e1;
    for (int msk = 32; msk; msk >>= 1) ss += __shfl_xor(ss, msk);
    p[i * 104 + lane] = e0 / ss;
    if (lane < 36) p[i * 104 + 64 + lane] = e1 / ss;
  }
  __syncthreads();
  int d0 = tj * 4;
  float oa[7][4];
#pragma unroll
  for (int r = 0; r < 7; ++r)
#pragma unroll
    for (int c = 0; c < 4; ++c) oa[r][c] = 0.f;
  for (int j = 0; j < Nn; ++j) {
    float pr[7];
#pragma unroll
    for (int r = 0; r < 7; ++r) pr[r] = p[(i0 + r) * 104 + j];
    float4 vv = *(const float4*)(vg + (size_t)j * 512 + d0);
#pragma unroll
    for (int r = 0; r < 7; ++r) {
      oa[r][0] += pr[r] * vv.x; oa[r][1] += pr[r] * vv.y;
      oa[r][2] += pr[r] * vv.z; oa[r][3] += pr[r] * vv.w;
    }
  }
  size_t ob = ((size_t)b * Nn) * 512 + h * 64 + d0;
#pragma unroll
  for (int r = 0; r < 7; ++r)
    if (i0 + r < Nn) {
      h4 hv, lv;
#pragma unroll
      for (int c = 0; c < 4; ++c) {
        _Float16 hh = (_Float16)oa[r][c];
        hv[c] = hh;
        lv[c] = (_Float16)(oa[r][c] - (float)hh);
      }
      *(h4*)(oh + ob + (size_t)(i0 + r) * 512) = hv;
      *(h4*)(ol + ob + (size_t)(i0 + r) * 512) = lv;
    }
}

// ---------------------------------------------------------------------------
// fp32 tiled GEMM (decode-loop small GEMMs only; split-K partials)
// ---------------------------------------------------------------------------
template<int BM, int BN, int BK, int TM, int TN>
__global__ __launch_bounds__(256) void gemm_k(
    const float* __restrict__ A, int lda,
    const float* __restrict__ B1, const float* __restrict__ B2, int splitB, int ldb,
    float* __restrict__ C, int ldc, int M, int N, int K, int kChunk)
{
  __shared__ __align__(16) float As[BK][BM + 4];
  __shared__ __align__(16) float Bs[BK][BN + 4];
  const int tid = threadIdx.x;
  const int m0 = blockIdx.y * BM;
  const int n0 = blockIdx.x * BN;
  const int k0 = blockIdx.z * kChunk;
  const int kEnd = k0 + kChunk;
  constexpr int TCOLS = BN / TN;
  const int tm = tid / TCOLS;
  const int tn = tid % TCOLS;
  float acc[TM][TN];
#pragma unroll
  for (int i = 0; i < TM; ++i)
#pragma unroll
    for (int j = 0; j < TN; ++j) acc[i][j] = 0.f;

  for (int kt = k0; kt < kEnd; kt += BK) {
    constexpr int A4 = BM * BK / 4;
    for (int c = tid; c < A4; c += 256) {
      int mm = c / (BK / 4);
      int k4 = (c % (BK / 4)) * 4;
      float4 av = *(const float4*)(A + (size_t)(m0 + mm) * lda + kt + k4);
      As[k4 + 0][mm] = av.x;
      As[k4 + 1][mm] = av.y;
      As[k4 + 2][mm] = av.z;
      As[k4 + 3][mm] = av.w;
    }
    constexpr int B4 = BK * BN / 4;
    for (int c = tid; c < B4; c += 256) {
      int kk = c / (BN / 4);
      int n4 = (c % (BN / 4)) * 4;
      int kgi = kt + kk;
      const float* Brow = (kgi < splitB) ? (B1 + (size_t)kgi * ldb)
                                         : (B2 + (size_t)(kgi - splitB) * ldb);
      *(float4*)&Bs[kk][n4] = *(const float4*)(Brow + n0 + n4);
    }
    __syncthreads();
#pragma unroll
    for (int kk = 0; kk < BK; ++kk) {
      float a[TM], b[TN];
#pragma unroll
      for (int i = 0; i < TM; ++i) a[i] = As[kk][tm * TM + i];
#pragma unroll
      for (int j = 0; j < TN; ++j) b[j] = Bs[kk][tn * TN + j];
#pragma unroll
      for (int i = 0; i < TM; ++i)
#pragma unroll
        for (int j = 0; j < TN; ++j)
          acc[i][j] += a[i] * b[j];
    }
    __syncthreads();
  }

  float* Cout = C + (size_t)blockIdx.z * (size_t)M * ldc;
#pragma unroll
  for (int i = 0; i < TM; ++i) {
    int m = m0 + tm * TM + i;
#pragma unroll
    for (int j = 0; j < TN; j += 4) {
      int n = n0 + tn * TN + j;
      float4 r;
      r.x = acc[i][j + 0]; r.y = acc[i][j + 1]; r.z = acc[i][j + 2]; r.w = acc[i][j + 3];
      *(float4*)(Cout + (size_t)m * ldc + n) = r;
    }
  }
}

// ---------------------------------------------------------------------------
// decode prep: gpw[e][c] = g[e]*pw[e][c];  uv = {u=col-sum(g*pw) | w=col-sum(b*pw)}
// ---------------------------------------------------------------------------
__global__ void gscale_k(const float* __restrict__ dpw, const float* __restrict__ g,
                         float* __restrict__ gpw)
{
  int i = blockIdx.x * 256 + threadIdx.x;     // < 512*512
  gpw[i] = g[i >> 9] * dpw[i];
}

__global__ void uv_k(const float* __restrict__ pw, const float* __restrict__ g,
                     const float* __restrict__ bb, float* __restrict__ uv)
{
  int c = blockIdx.x * 256 + threadIdx.x;
  float su = 0.f, sw = 0.f;
  for (int k = 0; k < 512; ++k) {
    float p = pw[(size_t)k * 512 + c];
    su += g[k] * p; sw += bb[k] * p;
  }
  uv[c] = su; uv[512 + c] = sw;
}

// ---------------------------------------------------------------------------
__global__ __launch_bounds__(256) void init_k(
    const float* __restrict__ emb, float* __restrict__ ctxh, float* __restrict__ cbuf,
    int* visited, int* ucount, int* complete, int* allvis, int* first, int* prev,
    float* out)
{
  int b = blockIdx.x, t = threadIdx.x;
#pragma unroll
  for (int r = 0; r < 2; ++r) {
    int e = t + 256 * r;
    float s = 0.f;
    for (int i = 0; i < Nn; ++i) s += emb[((size_t)b * Nn + i) * 512 + e];
    ctxh[(size_t)b * 1024 + e] = s / 100.f;
    ctxh[(size_t)b * 1024 + 512 + e] = 0.f;
    cbuf[(size_t)b * 512 + e] = 0.f;
  }
  if (t < Nn) visited[b * Nn + t] = 0;
  if (t == 0) {
    ucount[b] = 0; complete[b] = 0; allvis[b] = 0; first[b] = 0; prev[b] = 0;
    out[150 * Bb + b] = 0.f;
  }
}

__device__ __forceinline__ float sigm(float x) { return 1.f / (1.f + expf(-x)); }

__device__ __forceinline__ float4 add44(float4 a, float4 b, float4 c, float4 d)
{
  float4 r;
  r.x = a.x + b.x + c.x + d.x;
  r.y = a.y + b.y + c.y + d.y;
  r.z = a.z + b.z + c.z + d.z;
  r.w = a.w + b.w + c.w + d.w;
  return r;
}

// LSTM pointwise for 4 consecutive e (bit-identical add order to old lstm_pw_k)
__device__ __forceinline__ void lstm4(
    const float* __restrict__ gP, const float* __restrict__ bih,
    const float* __restrict__ bhh, const float* __restrict__ cin,
    int b, int e4, float4* h2o, float4* c2o)
{
  const float* g0 = gP + (size_t)b * 2048 + e4;
  const float* g1 = gP + 262144 + (size_t)b * 2048 + e4;
  float4 ig = add44(*(const float4*)(g0),
                    *(const float4*)(g1),
                    *(const float4*)(bih + e4),
                    *(const float4*)(bhh + e4));
  float4 fg = add44(*(const float4*)(g0 + 512),
                    *(const float4*)(g1 + 512),
                    *(const float4*)(bih + 512 + e4),
                    *(const float4*)(bhh + 512 + e4));
  float4 gg = add44(*(const float4*)(g0 + 1024),
                    *(const float4*)(g1 + 1024),
                    *(const float4*)(bih + 1024 + e4),
                    *(const float4*)(bhh + 1024 + e4));
  float4 og = add44(*(const float4*)(g0 + 1536),
                    *(const float4*)(g1 + 1536),
                    *(const float4*)(bih + 1536 + e4),
                    *(const float4*)(bhh + 1536 + e4));
  float4 cp = *(const float4*)(cin + (size_t)b * 512 + e4);
  float4 c2, h2;
  c2.x = sigm(fg.x) * cp.x + sigm(ig.x) * tanhf(gg.x);  h2.x = sigm(og.x) * tanhf(c2.x);
  c2.y = sigm(fg.y) * cp.y + sigm(ig.y) * tanhf(gg.y);  h2.y = sigm(og.y) * tanhf(c2.y);
  c2.z = sigm(fg.z) * cp.z + sigm(ig.z) * tanhf(gg.z);  h2.z = sigm(og.z) * tanhf(c2.z);
  c2.w = sigm(fg.w) * cp.w + sigm(ig.w) * tanhf(gg.w);  h2.w = sigm(og.w) * tanhf(c2.w);
  *h2o = h2; *c2o = c2;
}

// ---------------------------------------------------------------------------
// q-GEMM with LSTM pointwise fused into the A staging.
// Clone of gemm_k<32,64,16,2,4>, grid (8,4,8), K=512 split-z with kChunk=64.
// A[b][e] = h2(b,e) computed from gatesP partials + cin; x==0 blocks also
// write h2->ctxh[h-slot], c2->cout, and done partials dpart[z][b].
// ---------------------------------------------------------------------------
__global__ __launch_bounds__(256) void qh_gemm_k(
    const float* __restrict__ gP, const float* __restrict__ bih,
    const float* __restrict__ bhh, const float* __restrict__ cin,
    float* __restrict__ cout, const float* __restrict__ done_w,
    float* __restrict__ ctxh, const float* __restrict__ Bw,
    float* __restrict__ C, float* __restrict__ dpart)
{
  __shared__ __align__(16) float As[16][36];
  __shared__ __align__(16) float Bs[16][68];
  __shared__ float sPre[32][8];
  const int tid = threadIdx.x;
  const int m0 = blockIdx.y * 32;
  const int n0 = blockIdx.x * 64;
  const int z  = blockIdx.z;
  const int k0 = z * 64;
  const int tm = tid >> 4;          // TCOLS = 16
  const int tn = tid & 15;

  // --- state-write prepass (one writer block set covers each (b,e) once) ---
  if (blockIdx.x == 0) {
    int bl = tid >> 3;              // 0..31
    int el = (tid & 7) * 8;         // 0,8,..,56
    int gb = m0 + bl;
    float dsum = 0.f;
#pragma unroll
    for (int q = 0; q < 2; ++q) {
      int e = k0 + el + q * 4;
      float4 h2, c2;
      lstm4(gP, bih, bhh, cin, gb, e, &h2, &c2);
      *(float4*)(cout + (size_t)gb * 512 + e) = c2;
      *(float4*)(ctxh + (size_t)gb * 1024 + 512 + e) = h2;
      float4 dw = *(const float4*)(done_w + e);
      dsum += h2.x * dw.x + h2.y * dw.y + h2.z * dw.z + h2.w * dw.w;
    }
    sPre[bl][tid & 7] = dsum;
  }
  __syncthreads();
  if (blockIdx.x == 0 && tid < 32) {
    float s = 0.f;
#pragma unroll
    for (int q = 0; q < 8; ++q) s += sPre[tid][q];
    dpart[z * 128 + m0 + tid] = s;
  }

  float acc[2][4];
#pragma unroll
  for (int i = 0; i < 2; ++i)
#pragma unroll
    for (int j = 0; j < 4; ++j) acc[i][j] = 0.f;

  for (int kt = k0; kt < k0 + 64; kt += 16) {
    // stage A = h2 (recomputed; bit-identical to staged ctxh-h in old path)
    if (tid < 128) {
      int mm = tid >> 2;            // 0..31
      int k4 = (tid & 3) * 4;       // 0,4,8,12
      float4 h2, c2d;
      lstm4(gP, bih, bhh, cin, m0 + mm, kt + k4, &h2, &c2d);
      As[k4 + 0][mm] = h2.x;
      As[k4 + 1][mm] = h2.y;
      As[k4 + 2][mm] = h2.z;
      As[k4 + 3][mm] = h2.w;
    }
    // stage B (256 slots exactly)
    {
      int kk = tid >> 4;
      int n4 = (tid & 15) * 4;
      *(float4*)&Bs[kk][n4] = *(const float4*)(Bw + (size_t)(kt + kk) * 512 + n0 + n4);
    }
    __syncthreads();
#pragma unroll
    for (int kk = 0; kk < 16; ++kk) {
      float a[2], b[4];
      a[0] = As[kk][tm * 2 + 0];
      a[1] = As[kk][tm * 2 + 1];
#pragma unroll
      for (int j = 0; j < 4; ++j) b[j] = Bs[kk][tn * 4 + j];
#pragma unroll
      for (int i = 0; i < 2; ++i)
#pragma unroll
        for (int j = 0; j < 4; ++j) acc[i][j] += a[i] * b[j];
    }
    __syncthreads();
  }

  float* Cout = C + (size_t)z * 128 * 512;
#pragma unroll
  for (int i = 0; i < 2; ++i) {
    int m = m0 + tm * 2 + i;
    int n = n0 + tn * 4;
    float4 r;
    r.x = acc[i][0]; r.y = acc[i][1]; r.z = acc[i][2]; r.w = acc[i][3];
    *(float4*)(Cout + (size_t)m * 512 + n) = r;
  }
}

__global__ __launch_bounds__(128) void dec_attn_k(
    const float* __restrict__ qP, const float* __restrict__ bq,
    const float* __restrict__ Kd, const float* __restrict__ Vd,
    float* __restrict__ o)
{
  int bh = blockIdx.x; int b = bh >> 3, h = bh & 7;
  int t = threadIdx.x;
  __shared__ float qh[64];
  __shared__ float p[100];
  __shared__ float red[128];
  if (t < 64) {
    float s = bq[h * 64 + t];
#pragma unroll
    for (int s8 = 0; s8 < 8; ++s8) s += qP[(size_t)s8 * 65536 + (size_t)b * 512 + h * 64 + t];
    qh[t] = s;
  }
  __syncthreads();
  float scv = -3.4e38f;
  if (t < Nn) {
    const float* kr = Kd + ((size_t)b * Nn + t) * 512 + h * 64;
    float s = 0.f;
#pragma unroll
    for (int d = 0; d < 64; ++d) s += qh[d] * kr[d];
    scv = s * 0.125f;
  }
  red[t] = scv; __syncthreads();
  for (int o2 = 64; o2 > 0; o2 >>= 1) { if (t < o2) red[t] = fmaxf(red[t], red[t + o2]); __syncthreads(); }
  float m = red[0]; __syncthreads();
  float ex = (t < Nn) ? expf(scv - m) : 0.f;
  red[t] = ex; __syncthreads();
  for (int o2 = 64; o2 > 0; o2 >>= 1) { if (t < o2) red[t] += red[t + o2]; __syncthreads(); }
  float Z = red[0];
  if (t < Nn) p[t] = ex / Z;
  __syncthreads();
  if (t < 64) {
    float acc = 0.f;
    const float* vr = Vd + (size_t)b * Nn * 512 + h * 64 + t;
    for (int j = 0; j < Nn; ++j) acc += p[j] * vr[(size_t)j * 512];
    o[(size_t)b * 512 + h * 64 + t] = acc;
  }
}

// ---------------------------------------------------------------------------
// select3: complete-resolve (dpart) + dec_ln reduce (bit-identical mu/inv)
// + LN-folded pointer GEMV + scores/argmax/softmax/state (select2-verified).
// One block per batch row.
// ---------------------------------------------------------------------------
__global__ __launch_bounds__(256) void select3_k(
    const float* __restrict__ woP, const float* __restrict__ dbo,
    const float* __restrict__ gpw, const float* __restrict__ uv,
    const float* __restrict__ dpb,
    const float* __restrict__ emb, const float* __restrict__ ew,
    const float* __restrict__ dpart, const float* __restrict__ done_b,
    int* visited, int* ucount, int* complete, int* allvis, int* first, int* prev,
    float* __restrict__ ctxh, float* __restrict__ out,
    const float* __restrict__ sb_p, const float* __restrict__ rp_p, int step)
{
  int b = blockIdx.x, t = threadIdx.x;
  __shared__ __align__(16) float yv[512];
  __shared__ __align__(16) float lg[512];
  __shared__ float sc[128];
  __shared__ float red[256];
  __shared__ int redi[256];
  __shared__ int s_cm;
  __shared__ float s_mu, s_inv;

  if (t == 0) {
    float dp = 0.f;
#pragma unroll
    for (int z = 0; z < 8; ++z) dp += dpart[z * 128 + b];
    int cm = complete[b];
    if (!cm && ucount[b] >= Nn && step >= Nn && (dp + done_b[0]) > 0.f) {
      cm = 1; complete[b] = 1;
    }
    s_cm = cm;
  }

  // y = sum_z woP + dbo  (dec_ln-identical accumulation order)
  float v0 = dbo[t], v1 = dbo[t + 256];
#pragma unroll
  for (int s8 = 0; s8 < 8; ++s8) {
    v0 += woP[(size_t)s8 * 65536 + (size_t)b * 512 + t];
    v1 += woP[(size_t)s8 * 65536 + (size_t)b * 512 + t + 256];
  }
  yv[t] = v0; yv[t + 256] = v1;
  red[t] = v0 + v1; __syncthreads();
  for (int o = 128; o > 0; o >>= 1) { if (t < o) red[t] += red[t + o]; __syncthreads(); }
  float mu = red[0] * (1.f / 512.f);
  __syncthreads();
  float d0 = v0 - mu, d1 = v1 - mu;
  red[t] = d0 * d0 + d1 * d1; __syncthreads();
  for (int o = 128; o > 0; o >>= 1) { if (t < o) red[t] += red[t + o]; __syncthreads(); }
  if (t == 0) {
    s_mu = mu;
    s_inv = 1.f / sqrtf(red[0] * (1.f / 512.f) + 1e-5f);
  }
  __syncthreads();

  // logits GEMV with LN folded: lg[c] = inv*(y . gpw[:,c]) - inv*mu*u[c] + w[c] + dpb[c]
  {
    float acc0 = 0.f, acc1 = 0.f;
#pragma unroll 8
    for (int e = 0; e < 512; ++e) {
      float ye = yv[e];
      acc0 += ye * gpw[(size_t)e * 512 + t];
      acc1 += ye * gpw[(size_t)e * 512 + t + 256];
    }
    float inv = s_inv, m2 = s_inv * s_mu;
    lg[t]       = inv * acc0 - m2 * uv[t]       + uv[512 + t]       + dpb[t];
    lg[t + 256] = inv * acc1 - m2 * uv[t + 256] + uv[512 + t + 256] + dpb[t + 256];
  }
  __syncthreads();

  // scores + argmax + softmax + state update (select2-verified)
  if (t < Nn) {
    const float* er = emb + ((size_t)b * Nn + t) * 512;
    float s = 0.f;
#pragma unroll 8
    for (int e4 = 0; e4 < 128; ++e4) {
      float4 ev = *(const float4*)(er + e4 * 4);
      float4 lv = *(const float4*)(lg + e4 * 4);
      s += lv.x * ev.x + lv.y * ev.y + lv.z * ev.z + lv.w * ev.w;
    }
    int av = allvis[b];
    if (!av && visited[b * Nn + t]) s = rp_p[0];
    if (av) {
      int pv = prev[b];
      float direct = ew[(size_t)b * 10000 + (size_t)pv * 100];
      float via = ew[(size_t)b * 10000 + (size_t)pv * 100 + t] + ew[(size_t)b * 10000 + (size_t)t * 100];
      if (via < direct) s += sb_p[0] * (direct - via) / direct;
    }
    if (s_cm) s = (t == first[b]) ? 100.f : -1e9f;
    sc[t] = s;
  }
  __syncthreads();
  float vv = (t < Nn) ? sc[t] : -3.4e38f;
  int ii = (t < Nn) ? t : 0x7fffffff;
  red[t] = vv; redi[t] = ii;
  __syncthreads();
  for (int o = 128; o > 0; o >>= 1) {
    if (t < o) {
      float v2 = red[t + o]; int i2 = redi[t + o];
      if (v2 > red[t] || (v2 == red[t] && i2 < redi[t])) { red[t] = v2; redi[t] = i2; }
    }
    __syncthreads();
  }
  float m = red[0];
  int curr = redi[0];
  __syncthreads();
  float ex = (t < Nn) ? expf(sc[t] - m) : 0.f;
  red[t] = ex; __syncthreads();
  for (int o = 128; o > 0; o >>= 1) { if (t < o) red[t] += red[t + o]; __syncthreads(); }
  float Z = red[0];
  if (t == 0) {
    float pcur = expf(sc[curr] - m) / Z;
    out[step * Bb + b] = logf(pcur + 1e-10f);
    out[(151 + step) * Bb + b] = (float)curr;
    if (!s_cm) {
      if (!visited[b * Nn + curr]) ucount[b] = ucount[b] + 1;
      visited[b * Nn + curr] = 1;
    }
    if (ucount[b] >= Nn) allvis[b] = 1;
    if (step == 0) first[b] = curr;
    prev[b] = curr;
  }
  const float* src = emb + ((size_t)b * Nn + curr) * 512;
  ctxh[(size_t)b * 1024 + t] = src[t];
  ctxh[(size_t)b * 1024 + t + 256] = src[t + 256];
}

__global__ void final_k(const int* complete, const int* first, float* out)
{
  int b = threadIdx.x;
  out[(151 + 150) * Bb + b] = complete[b] ? 0.f : (float)first[b];
}

// ---------------------------------------------------------------------------
extern "C" void kernel_launch(void* const* d_in, const int* in_sizes, int n_in,
                              void* d_out, int out_size, void* d_ws, size_t ws_size,
                              hipStream_t stream)
{
  const float* nf      = (const float*)d_in[0];
  const float* ew      = (const float*)d_in[1];
  const float* pe      = (const float*)d_in[2];
  const float* in_w    = (const float*)d_in[3];
  const float* in_b    = (const float*)d_in[4];
  const float* enc_wq  = (const float*)d_in[5];
  const float* enc_wk  = (const float*)d_in[6];
  const float* enc_wv  = (const float*)d_in[7];
  const float* enc_wo  = (const float*)d_in[8];
  const float* enc_bq  = (const float*)d_in[9];
  const float* enc_bk  = (const float*)d_in[10];
  const float* enc_bv  = (const float*)d_in[11];
  const float* enc_bo  = (const float*)d_in[12];
  const float* enc_w1  = (const float*)d_in[13];
  const float* enc_b1  = (const float*)d_in[14];
  const float* enc_w2  = (const float*)d_in[15];
  const float* enc_b2  = (const float*)d_in[16];
  const float* ln1g    = (const float*)d_in[17];
  const float* ln1b    = (const float*)d_in[18];
  const float* ln2g    = (const float*)d_in[19];
  const float* ln2b    = (const float*)d_in[20];
  const float* wih     = (const float*)d_in[21];
  const float* whh     = (const float*)d_in[22];
  const float* bih     = (const float*)d_in[23];
  const float* bhh     = (const float*)d_in[24];
  const float* dwq     = (const float*)d_in[25];
  const float* dwk     = (const float*)d_in[26];
  const float* dwv     = (const float*)d_in[27];
  const float* dwo     = (const float*)d_in[28];
  const float* dpw     = (const float*)d_in[29];
  const float* dbq     = (const float*)d_in[30];
  const float* dbk     = (const float*)d_in[31];
  const float* dbv     = (const float*)d_in[32];
  const float* dbo     = (const float*)d_in[33];
  const float* dpb     = (const float*)d_in[34];
  const float* dlng    = (const float*)d_in[35];
  const float* dlnb    = (const float*)d_in[36];
  const float* sbp     = (const float*)d_in[37];
  const float* rpp     = (const float*)d_in[38];
  const float* done_w  = (const float*)d_in[39];
  const float* done_b  = (const float*)d_in[40];
  float* out = (float*)d_out;

  // ---- workspace carve ----
  const size_t SZ = 12800ull * 512;            // 6,553,600 elements
  float* ws = (float*)d_ws;
  float* x   = ws;                              // fp32 node emb
  float* xq  = x + SZ;                          // q / wo-out / ff2-out
  float* xk  = xq + SZ;                         // enc k -> dec K
  float* xv  = xk + SZ;                         // enc v -> FF2 partials -> dec V
  _Float16* xh = (_Float16*)(xv + SZ);          // x hi plane
  _Float16* xl = xh + SZ;                       // x lo plane
  _Float16* oh = xl + SZ;                       // attn-out hi  (alias: FF1-out hi)
  _Float16* ol = oh + SZ;                       // attn-out lo  (alias: FF1-out lo)
  _Float16* wb = ol + SZ;                       // weight planes, 6,291,456 f16
  _Float16* wqh = wb;               _Float16* wql = wqh + 262144;
  _Float16* wkh = wql + 262144;     _Float16* wkl = wkh + 262144;
  _Float16* wvh = wkl + 262144;     _Float16* wvl = wvh + 262144;
  _Float16* woh_ = wvl + 262144;    _Float16* wol_ = woh_ + 262144;
  _Float16* w1h = wol_ + 262144;    _Float16* w1l = w1h + 1048576;
  _Float16* w2h = w1l + 1048576;    _Float16* w2l = w2h + 1048576;
  float* ctxh   = (float*)(w2l + 1048576);      // 128 x 1024 [ctx | h]
  float* cbufA  = ctxh + 131072;                // 128 x 512  c-state ping
  float* gatesP = cbufA + 65536;                // 2 x 128 x 2048
  float* qP     = gatesP + 524288;              // 8 x 128 x 512
  float* woP    = qP + 524288;
  float* gpw    = woP + 524288;                 // 512 x 512  (was pwP slot)
  float* uvv    = gpw + 262144;                 // 1024 {u|w}
  float* dpart  = uvv + 1024;                   // 8 x 128
  float* cbufB  = gpw + 524288;                 // 128 x 512  c-state pong (was abuf)
  float* dbuf   = cbufB + 65536;                // 128 x 512 dec-attn out
  int* ivis     = (int*)(dbuf + 65536);
  int* ucount   = ivis + 12800;
  int* complete = ucount + 128;
  int* allvis   = complete + 128;
  int* first    = allvis + 128;
  int* prev     = first + 128;

  // ---- encoder ----
  input_proj_k<<<25600, 256, 0, stream>>>(nf, in_w, in_b, pe, x, xh, xl);

  for (int l = 0; l < Ll; ++l) {
    const float* wq = enc_wq + (size_t)l * 262144;
    const float* wk = enc_wk + (size_t)l * 262144;
    const float* wv = enc_wv + (size_t)l * 262144;
    const float* wo = enc_wo + (size_t)l * 262144;
    const float* bq = enc_bq + (size_t)l * 512;
    const float* bk = enc_bk + (size_t)l * 512;
    const float* bv = enc_bv + (size_t)l * 512;
    const float* bo = enc_bo + (size_t)l * 512;
    const float* w1 = enc_w1 + (size_t)l * 1048576;
    const float* b1 = enc_b1 + (size_t)l * 2048;
    const float* w2 = enc_w2 + (size_t)l * 1048576;
    const float* b2 = enc_b2 + (size_t)l * 512;

    wconv_k<<<dim3(16, 16), 256, 0, stream>>>(wq, 512, 512, wqh, wql);
    wconv_k<<<dim3(16, 16), 256, 0, stream>>>(wk, 512, 512, wkh, wkl);
    wconv_k<<<dim3(16, 16), 256, 0, stream>>>(wv, 512, 512, wvh, wvl);
    wconv_k<<<dim3(16, 16), 256, 0, stream>>>(wo, 512, 512, woh_, wol_);
    wconv_k<<<dim3(64, 16), 256, 0, stream>>>(w1, 512, 2048, w1h, w1l);
    wconv_k<<<dim3(16, 64), 256, 0, stream>>>(w2, 2048, 512, w2h, w2l);

    mgemm_k<false, true, true, false><<<dim3(4, 100), 256, 0, stream>>>(
        xh, xl, 512, wqh, wql, 512, xq, nullptr, nullptr, 512, bq, 512, 0, 0);
    mgemm_k<false, true, true, false><<<dim3(4, 100), 256, 0, stream>>>(
        xh, xl, 512, wkh, wkl, 512, xk, nullptr, nullptr, 512, bk, 512, 0, 0);
    mgemm_k<false, true, true, false><<<dim3(4, 100), 256, 0, stream>>>(
        xh, xl, 512, wvh, wvl, 512, xv, nullptr, nullptr, 512, bv, 512, 0, 0);
    enc_attn_k<<<1024, 256, 0, stream>>>(xq, xk, xv, oh, ol);
    mgemm_k<false, true, true, false><<<dim3(4, 100), 256, 0, stream>>>(
        oh, ol, 512, woh_, wol_, 512, xq, nullptr, nullptr, 512, bo, 512, 0, 0);
    ln_k<<<12800, 256, 0, stream>>>(x, xq, ln1g + l * 512, ln1b + l * 512, x, xh, xl);
    for (int c = 0; c < 4; ++c) {
      mgemm_k<true, true, false, false><<<dim3(16, 25), 256, 0, stream>>>(
          xh + (size_t)c * 3200 * 512, xl + (size_t)c * 3200 * 512, 512,
          w1h, w1l, 512, nullptr, oh, ol, 2048, b1, 512, 0, 0);
      mgemm_k<false, false, true, true><<<dim3(4, 25, 4), 256, 0, stream>>>(
          oh, ol, 2048, w2h, w2l, 2048, xv, nullptr, nullptr, 512,
          nullptr, 2048, 512, 3200);
      reduce4_k<<<6400, 256, 0, stream>>>(xv, b2, xq + (size_t)c * 3200 * 512);
    }
    ln_k<<<12800, 256, 0, stream>>>(x, xq, ln2g + l * 512, ln2b + l * 512, x, xh, xl);
  }

  // ---- decode prep: K/V step-invariant ----
  wconv_k<<<dim3(16, 16), 256, 0, stream>>>(dwk, 512, 512, wqh, wql);
  wconv_k<<<dim3(16, 16), 256, 0, stream>>>(dwv, 512, 512, wkh, wkl);
  mgemm_k<false, true, true, false><<<dim3(4, 100), 256, 0, stream>>>(
      xh, xl, 512, wqh, wql, 512, xk, nullptr, nullptr, 512, dbk, 512, 0, 0);
  mgemm_k<false, true, true, false><<<dim3(4, 100), 256, 0, stream>>>(
      xh, xl, 512, wkh, wkl, 512, xv, nullptr, nullptr, 512, dbv, 512, 0, 0);
  gscale_k<<<1024, 256, 0, stream>>>(dpw, dlng, gpw);
  uv_k<<<2, 256, 0, stream>>>(dpw, dlng, dlnb, uvv);
  init_k<<<128, 256, 0, stream>>>(x, ctxh, cbufA, ivis, ucount, complete, allvis, first, prev, out);

  // ---- decode loop: 5 kernels/step ----
  float* cin = cbufA;
  float* cout = cbufB;
  for (int step = 0; step < STEPS; ++step) {
    gemm_k<32, 64, 16, 2, 4><<<dim3(32, 4, 2), 256, 0, stream>>>(
        ctxh, 1024, wih, whh, 512, 2048, gatesP, 2048, 128, 2048, 1024, 512);
    qh_gemm_k<<<dim3(8, 4, 8), 256, 0, stream>>>(
        gatesP, bih, bhh, cin, cout, done_w, ctxh, dwq, qP, dpart);
    dec_attn_k<<<1024, 128, 0, stream>>>(qP, dbq, xk, xv, dbuf);
    gemm_k<32, 64, 16, 2, 4><<<dim3(8, 4, 8), 256, 0, stream>>>(
        dbuf, 512, dwo, dwo, 1 << 30, 512, woP, 512, 128, 512, 512, 64);
    select3_k<<<128, 256, 0, stream>>>(woP, dbo, gpw, uvv, dpb, x, ew, dpart, done_b,
                                       ivis, ucount, complete, allvis, first, prev,
                                       ctxh, out, sbp, rpp, step);
    float* tmp = cin; cin = cout; cout = tmp;
  }
  final_k<<<1, 128, 0, stream>>>(complete, first, out);
}